// Round 2
// baseline (230.582 us; speedup 1.0000x reference)
//
#include <hip/hip_runtime.h>
#include <hip/hip_bf16.h>
#include <stdint.h>

typedef __attribute__((ext_vector_type(8))) short bf16x8;
typedef __attribute__((ext_vector_type(4))) float f32x4;

__device__ __forceinline__ unsigned short f2bf(float f) {
    union { float f; unsigned u; } v; v.f = f;
    unsigned u = v.u;
    u += 0x7fff + ((u >> 16) & 1);   // round-to-nearest-even
    return (unsigned short)(u >> 16);
}

// ---------------------------------------------------------------------------
// prep: blocks [0, nbBin): binner (slot claim per feature).
//       blocks [nbBin, nbBin+nbW): convert W0..W3 fp32 -> bf16 into wsW.
// ---------------------------------------------------------------------------
__global__ __launch_bounds__(256) void prep(
    const int* __restrict__ FI, const int* __restrict__ wptr,
    int* __restrict__ cnt, int* __restrict__ slots,
    const float* __restrict__ W0, const float* __restrict__ W1,
    const float* __restrict__ W2, const float* __restrict__ W3,
    unsigned short* __restrict__ wsW,
    int NF, int HW, int wsz, int nbBin)
{
    int blk = blockIdx.x;
    if (blk < nbBin) {
        int i = blk * 256 + threadIdx.x;
        if (i >= NF) return;
        int Wd = *wptr;
        int b = FI[(size_t)i * 3];
        int h = FI[(size_t)i * 3 + 1];
        int w = FI[(size_t)i * 3 + 2];
        int gc = b * HW + h * Wd + w;
        int slot = atomicAdd(&cnt[gc], 1);
        if (slot < 16) slots[(size_t)gc * 16 + slot] = i;
    } else {
        int idx = ((blk - nbBin) * 256 + threadIdx.x) * 4;
        if (idx >= 4 * wsz) return;
        int l = idx / wsz, off = idx - l * wsz;
        const float* Ws = (l == 0) ? W0 : (l == 1) ? W1 : (l == 2) ? W2 : W3;
        float4 v = *(const float4*)(Ws + off);
        ushort4 o; o.x = f2bf(v.x); o.y = f2bf(v.y); o.z = f2bf(v.z); o.w = f2bf(v.w);
        *(ushort4*)(wsW + (size_t)l * wsz + off) = o;
    }
}

// ---------------------------------------------------------------------------
// mlp_k: fused 4-layer MLP, 16 query rows x 256 N per block, LDS ping-pong.
// Split out of the old gather_mlp (gather moved into cell_gemm4).
// ---------------------------------------------------------------------------
__global__ __launch_bounds__(256) void mlp_k(
    const float* __restrict__ Qf, const unsigned short* __restrict__ Wb,
    const float* __restrict__ b0p, const float* __restrict__ b1p,
    const float* __restrict__ b2p, const float* __restrict__ b3p,
    unsigned short* __restrict__ outQB, int M, int wsz)
{
    __shared__ unsigned short At[16 * 264];
    const int tid = threadIdx.x;
    const int wid = tid >> 6, lane = tid & 63, quad = lane >> 4, l16 = lane & 15;

    const int m0 = blockIdx.x * 16;
    #pragma unroll
    for (int i = 0; i < 4; ++i) {
        int c = tid + i * 256;
        int row = c >> 6, kq = (c & 63) * 4;
        int gr = m0 + row; if (gr >= M) gr = M - 1;
        float4 v = *(const float4*)(Qf + (size_t)gr * 256 + kq);
        ushort4 o; o.x = f2bf(v.x); o.y = f2bf(v.y); o.z = f2bf(v.z); o.w = f2bf(v.w);
        *(ushort4*)&At[row * 264 + kq] = o;
    }
    __syncthreads();

    for (int l = 0; l < 4; ++l) {
        const unsigned short* Wl = Wb + (size_t)l * wsz;
        const float* bl = (l == 0) ? b0p : (l == 1) ? b1p : (l == 2) ? b2p : b3p;
        f32x4 acc[4] = {};
        #pragma unroll
        for (int k = 0; k < 256; k += 32) {
            bf16x8 af = *(const bf16x8*)&At[l16 * 264 + k + quad * 8];
            #pragma unroll
            for (int t = 0; t < 4; ++t) {
                int n = wid * 64 + t * 16 + l16;
                bf16x8 bfr = *(const bf16x8*)(Wl + (size_t)n * 256 + k + quad * 8);
                acc[t] = __builtin_amdgcn_mfma_f32_16x16x32_bf16(af, bfr, acc[t], 0, 0, 0);
            }
        }
        __syncthreads();
        #pragma unroll
        for (int t = 0; t < 4; ++t) {
            int n = wid * 64 + t * 16 + l16;
            float bv = bl[n];
            #pragma unroll
            for (int r = 0; r < 4; ++r) {
                int m = quad * 4 + r;
                float v = acc[t][r] + bv;
                if (l < 3) {
                    At[m * 264 + n] = f2bf(fmaxf(v, 0.f));
                } else {
                    if (m0 + m < M) outQB[(size_t)(m0 + m) * 256 + n] = f2bf(v);
                }
            }
        }
        if (l < 3) __syncthreads();
    }
}

// ---------------------------------------------------------------------------
// cell_gemm4: FUSED gather + gemm. Each block gathers its 64 cells' feature
// sums straight into an LDS A-tile (bf16, row-padded +8 to fix the 512B-stride
// bank conflict), then runs the Bsm-staged MFMA loop. Eliminates the 64 MB
// Abuf round-trip and hides FV random-read latency under co-resident blocks'
// MFMA phases. LDS 58.1 KB -> 2 blocks/CU (1024 blocks = 2 rounds).
// ---------------------------------------------------------------------------
__global__ __launch_bounds__(256, 2) void cell_gemm4(
    const float* __restrict__ FV, const int* __restrict__ cnt,
    const int* __restrict__ slots,
    const unsigned short* __restrict__ QB, const int* __restrict__ qoff,
    float* __restrict__ out, int cpb, int HW, int Qstride)
{
    __shared__ unsigned short Asm[64 * 264];   // 33792 B (pad 8 bf16/row)
    __shared__ unsigned short Bsm[304 * 40];   // 24320 B

    const int tid = threadIdx.x;
    const int b   = blockIdx.x / cpb;
    const int c0  = (blockIdx.x - b * cpb) * 64;
    const size_t gc0 = (size_t)b * HW + c0;
    const int q0 = qoff[b];
    int qlen = qoff[b + 1] - q0; if (qlen < 1) qlen = 1;

    const int wid = tid >> 6, lane = tid & 63, quad = lane >> 4, l16 = lane & 15;

    // ---- gather phase: 64 cells -> Asm. quad-per-cell, 4 iterations/wave ----
    #pragma unroll
    for (int j = 0; j < 4; ++j) {
        int rb = wid * 16 + j * 4;                 // local row base (4 cells)
        int sl = slots[(gc0 + rb) * 16 + lane];    // coalesced 64-int load
        int r  = rb + quad;                        // this quad's local cell
        int n  = cnt[gc0 + r];                     // broadcast within quad
        if (n > 16) n = 16;
        float4 a0 = make_float4(0.f, 0.f, 0.f, 0.f);
        float4 a1 = a0, a2 = a0, a3 = a0;
        for (int s = 0; s < n; ++s) {
            int f = __shfl(sl, (quad << 4) + s);
            const float* src = FV + (size_t)f * 256 + l16 * 16;
            float4 v0 = *(const float4*)(src + 0);
            float4 v1 = *(const float4*)(src + 4);
            float4 v2 = *(const float4*)(src + 8);
            float4 v3 = *(const float4*)(src + 12);
            a0.x += v0.x; a0.y += v0.y; a0.z += v0.z; a0.w += v0.w;
            a1.x += v1.x; a1.y += v1.y; a1.z += v1.z; a1.w += v1.w;
            a2.x += v2.x; a2.y += v2.y; a2.z += v2.z; a2.w += v2.w;
            a3.x += v3.x; a3.y += v3.y; a3.z += v3.z; a3.w += v3.w;
        }
        // zero-feature cells store zeros (row must be cleared)
        unsigned short* dst = &Asm[r * 264 + l16 * 16];
        ushort4 o0, o1, o2, o3;
        o0.x = f2bf(a0.x); o0.y = f2bf(a0.y); o0.z = f2bf(a0.z); o0.w = f2bf(a0.w);
        o1.x = f2bf(a1.x); o1.y = f2bf(a1.y); o1.z = f2bf(a1.z); o1.w = f2bf(a1.w);
        o2.x = f2bf(a2.x); o2.y = f2bf(a2.y); o2.z = f2bf(a2.z); o2.w = f2bf(a2.w);
        o3.x = f2bf(a3.x); o3.y = f2bf(a3.y); o3.z = f2bf(a3.z); o3.w = f2bf(a3.w);
        *(ushort4*)(dst + 0)  = o0;
        *(ushort4*)(dst + 4)  = o1;
        *(ushort4*)(dst + 8)  = o2;
        *(ushort4*)(dst + 12) = o3;
    }
    __syncthreads();

    // ---- gemm phase: A from LDS, B staged per k-step ----
    const int arow = (wid * 16 + l16) * 264 + quad * 8;
    f32x4 acc[19] = {};

    for (int k0 = 0; k0 < 256; k0 += 32) {
        for (int c = tid; c < 1216; c += 256) {
            int row = c >> 2, kc = (c & 3) * 8;
            int qr = row < qlen ? row : qlen - 1;
            uint4 v = *(const uint4*)(QB + (size_t)(q0 + qr) * 256 + k0 + kc);
            *(uint4*)&Bsm[row * 40 + kc] = v;
        }
        __syncthreads();
        bf16x8 afA = *(const bf16x8*)&Asm[arow + k0];
        #pragma unroll
        for (int t = 0; t < 19; ++t) {
            bf16x8 bfr = *(const bf16x8*)&Bsm[(t * 16 + l16) * 40 + quad * 8];
            acc[t] = __builtin_amdgcn_mfma_f32_16x16x32_bf16(afA, bfr, acc[t], 0, 0, 0);
        }
        __syncthreads();
    }

    // coalesced stores; zero-fill n >= qlen (no memset of d_out needed)
    #pragma unroll
    for (int r = 0; r < 4; ++r) {
        int m = quad * 4 + r;
        float* dst = out + (gc0 + wid * 16 + m) * Qstride;
        #pragma unroll
        for (int t = 0; t < 19; ++t) {
            int nq = t * 16 + l16;
            if (nq < Qstride) dst[nq] = (nq < qlen) ? acc[t][r] : 0.f;
        }
    }
}

extern "C" void kernel_launch(void* const* d_in, const int* in_sizes, int n_in,
                              void* d_out, int out_size, void* d_ws, size_t ws_size,
                              hipStream_t stream) {
    const float* queries = (const float*)d_in[0];
    const float* FV      = (const float*)d_in[1];
    const int*   FI      = (const int*)d_in[2];
    const int*   qoff    = (const int*)d_in[3];
    const int*   wptr    = (const int*)d_in[6];
    const float* W0 = (const float*)d_in[7];
    const float* b0 = (const float*)d_in[8];
    const float* W1 = (const float*)d_in[9];
    const float* b1 = (const float*)d_in[10];
    const float* W2 = (const float*)d_in[11];
    const float* b2 = (const float*)d_in[12];
    const float* W3 = (const float*)d_in[13];
    const float* b3 = (const float*)d_in[14];
    float* out = (float*)d_out;

    const int NQe = in_sizes[0];          // 307200
    const int NQ  = NQe / 256;            // 1200
    const int NF  = in_sizes[1] / 256;    // 65536
    const int WSZ = in_sizes[7];          // 65536
    const int B   = in_sizes[3] - 1;      // 4
    const int Q   = NQ / B;               // 300
    const int HW  = out_size / (B * Q);   // 16384
    const int NC  = B * HW;               // 65536 cells
    const int cpb = HW / 64;              // 256 blocks per batch

    int* cnt   = (int*)d_ws;                                   // NC ints
    int* slots = cnt + (size_t)NC;                             // NC*16 ints
    unsigned short* wsW  = (unsigned short*)(slots + (size_t)NC * 16);  // 4*WSZ
    unsigned short* wsQB = wsW + (size_t)4 * WSZ;              // NQe bf16

    hipMemsetAsync(cnt, 0, (size_t)NC * sizeof(int), stream);

    const int nbBin = (NF + 255) / 256;
    const int nbW   = (4 * WSZ / 4 + 255) / 256;
    prep<<<nbBin + nbW, 256, 0, stream>>>(FI, wptr, cnt, slots,
                                          W0, W1, W2, W3, wsW, NF, HW, WSZ, nbBin);

    const int nbM = (NQ + 15) / 16;       // 75 mlp blocks
    mlp_k<<<nbM, 256, 0, stream>>>(queries, wsW, b0, b1, b2, b3, wsQB, NQ, WSZ);

    cell_gemm4<<<B * cpb, 256, 0, stream>>>(FV, cnt, slots, wsQB, qoff,
                                            out, cpb, HW, Q);
}

// Round 4
// 198.933 us; speedup vs baseline: 1.1591x; 1.1591x over previous
//
#include <hip/hip_runtime.h>
#include <hip/hip_bf16.h>
#include <stdint.h>

typedef __attribute__((ext_vector_type(8))) short bf16x8;
typedef __attribute__((ext_vector_type(4))) float f32x4;

__device__ __forceinline__ unsigned short f2bf(float f) {
    union { float f; unsigned u; } v; v.f = f;
    unsigned u = v.u;
    u += 0x7fff + ((u >> 16) & 1);   // round-to-nearest-even
    return (unsigned short)(u >> 16);
}

// ---------------------------------------------------------------------------
// prep: blocks [0, nbBin): binner (slot claim per feature).
//       blocks [nbBin, nbBin+nbW): convert W0..W3 fp32 -> bf16 into wsW.
// ---------------------------------------------------------------------------
__global__ __launch_bounds__(256) void prep(
    const int* __restrict__ FI, const int* __restrict__ wptr,
    int* __restrict__ cnt, int* __restrict__ slots,
    const float* __restrict__ W0, const float* __restrict__ W1,
    const float* __restrict__ W2, const float* __restrict__ W3,
    unsigned short* __restrict__ wsW,
    int NF, int HW, int wsz, int nbBin)
{
    int blk = blockIdx.x;
    if (blk < nbBin) {
        int i = blk * 256 + threadIdx.x;
        if (i >= NF) return;
        int Wd = *wptr;
        int b = FI[(size_t)i * 3];
        int h = FI[(size_t)i * 3 + 1];
        int w = FI[(size_t)i * 3 + 2];
        int gc = b * HW + h * Wd + w;
        int slot = atomicAdd(&cnt[gc], 1);
        if (slot < 16) slots[(size_t)gc * 16 + slot] = i;
    } else {
        int idx = ((blk - nbBin) * 256 + threadIdx.x) * 4;
        if (idx >= 4 * wsz) return;
        int l = idx / wsz, off = idx - l * wsz;
        const float* Ws = (l == 0) ? W0 : (l == 1) ? W1 : (l == 2) ? W2 : W3;
        float4 v = *(const float4*)(Ws + off);
        ushort4 o; o.x = f2bf(v.x); o.y = f2bf(v.y); o.z = f2bf(v.z); o.w = f2bf(v.w);
        *(ushort4*)(wsW + (size_t)l * wsz + off) = o;
    }
}

// ---------------------------------------------------------------------------
// gather_mlp: blocks [0, nbM): fused 4-layer MLP.
//             blocks [nbM, nbM+nbG): cell gather, HALF-WAVE per cell.
// Access-granularity layout (the theory under test):
//   - lane hl (= lane&31) owns cols {hl*4..+3} and {128+hl*4..+3} of its cell
//   - FV loads: float4, 16B lane stride -> 512B contiguous per instruction
//   - Abuf stores: ushort4, 8B lane stride -> 256B contiguous per instruction;
//     each 64B line written whole by ONE instruction (no L2 partial-line RMW).
// Divergence fix vs round 3: loop bound nmax is WAVE-UNIFORM (max of the two
// halves' counts) so every __shfl executes with all 64 lanes active; the FV
// load/accumulate is predicated with s < n. ds_bpermute from inactive lanes
// (the round-3 bug) can no longer happen.
// ---------------------------------------------------------------------------
__global__ __launch_bounds__(256) void gather_mlp(
    // mlp args
    const float* __restrict__ Qf, const unsigned short* __restrict__ Wb,
    const float* __restrict__ b0p, const float* __restrict__ b1p,
    const float* __restrict__ b2p, const float* __restrict__ b3p,
    unsigned short* __restrict__ outQB, int M, int wsz,
    // gather args
    const float* __restrict__ FV, const int* __restrict__ cnt,
    const int* __restrict__ slots, unsigned short* __restrict__ Abuf, int NC,
    int nbM, int nbG)
{
    __shared__ unsigned short At[16 * 264];
    const int tid = threadIdx.x;
    const int wid = tid >> 6, lane = tid & 63, quad = lane >> 4, l16 = lane & 15;

    if (blockIdx.x >= nbM) {
        // ------------- gather: half-wave per cell, 4 cells per wave -------------
        const int hl  = lane & 31;      // half-lane
        const int hid = lane >> 5;      // which half of the wave
        const int wg = (blockIdx.x - nbM) * 4 + wid;
        const int nw = nbG * 4;
        for (int cb = wg * 4; cb < NC; cb += nw * 4) {
            int sl = slots[(size_t)cb * 16 + lane];   // 4 cells' slots, coalesced
            #pragma unroll
            for (int i = 0; i < 2; ++i) {
                int j = i * 2 + hid;                  // this half's cell (of the 4)
                int c = cb + j;
                // wave-uniform counts for the pair of cells handled this pass
                int nA = cnt[cb + i * 2];     if (nA > 16) nA = 16;
                int nB = cnt[cb + i * 2 + 1]; if (nB > 16) nB = 16;
                int n    = hid ? nB : nA;             // own trip count
                int nmax = nA > nB ? nA : nB;         // wave-uniform bound
                float4 a0 = make_float4(0.f, 0.f, 0.f, 0.f);
                float4 a1 = a0;
                for (int s = 0; s < nmax; ++s) {
                    int f = __shfl(sl, j * 16 + s);   // ALL lanes active here
                    if (s < n) {
                        const float* src = FV + (size_t)f * 256 + hl * 4;
                        float4 v0 = *(const float4*)(src);         // cols hl*4
                        float4 v1 = *(const float4*)(src + 128);   // cols 128+hl*4
                        a0.x += v0.x; a0.y += v0.y; a0.z += v0.z; a0.w += v0.w;
                        a1.x += v1.x; a1.y += v1.y; a1.z += v1.z; a1.w += v1.w;
                    }
                }
                ushort4 o0, o1;
                o0.x = f2bf(a0.x); o0.y = f2bf(a0.y); o0.z = f2bf(a0.z); o0.w = f2bf(a0.w);
                o1.x = f2bf(a1.x); o1.y = f2bf(a1.y); o1.z = f2bf(a1.z); o1.w = f2bf(a1.w);
                unsigned short* dst = Abuf + (size_t)c * 256;
                *(ushort4*)(dst + hl * 4)       = o0;   // 256B contiguous/instr
                *(ushort4*)(dst + 128 + hl * 4) = o1;   // 256B contiguous/instr
            }
        }
        return;
    }

    // ---------------- mlp: 16 query rows x 256 N, LDS ping-pong ----------------
    const int m0 = blockIdx.x * 16;
    #pragma unroll
    for (int i = 0; i < 4; ++i) {
        int c = tid + i * 256;
        int row = c >> 6, kq = (c & 63) * 4;
        int gr = m0 + row; if (gr >= M) gr = M - 1;
        float4 v = *(const float4*)(Qf + (size_t)gr * 256 + kq);
        ushort4 o; o.x = f2bf(v.x); o.y = f2bf(v.y); o.z = f2bf(v.z); o.w = f2bf(v.w);
        *(ushort4*)&At[row * 264 + kq] = o;
    }
    __syncthreads();

    for (int l = 0; l < 4; ++l) {
        const unsigned short* Wl = Wb + (size_t)l * wsz;
        const float* bl = (l == 0) ? b0p : (l == 1) ? b1p : (l == 2) ? b2p : b3p;
        f32x4 acc[4] = {};
        #pragma unroll
        for (int k = 0; k < 256; k += 32) {
            bf16x8 af = *(const bf16x8*)&At[l16 * 264 + k + quad * 8];
            #pragma unroll
            for (int t = 0; t < 4; ++t) {
                int n = wid * 64 + t * 16 + l16;
                bf16x8 bfr = *(const bf16x8*)(Wl + (size_t)n * 256 + k + quad * 8);
                acc[t] = __builtin_amdgcn_mfma_f32_16x16x32_bf16(af, bfr, acc[t], 0, 0, 0);
            }
        }
        __syncthreads();
        #pragma unroll
        for (int t = 0; t < 4; ++t) {
            int n = wid * 64 + t * 16 + l16;
            float bv = bl[n];
            #pragma unroll
            for (int r = 0; r < 4; ++r) {
                int m = quad * 4 + r;
                float v = acc[t][r] + bv;
                if (l < 3) {
                    At[m * 264 + n] = f2bf(fmaxf(v, 0.f));
                } else {
                    if (m0 + m < M) outQB[(size_t)(m0 + m) * 256 + n] = f2bf(v);
                }
            }
        }
        if (l < 3) __syncthreads();
    }
}

// ---------------------------------------------------------------------------
// cell_gemm3: B-only LDS (24.3 KB -> 4 blocks/CU, all 1024 blocks resident).
// A-fragments read per-wave straight from L3-hot Abuf (16B/lane), prefetched
// one K-step ahead. No atomics, no memset.
// ---------------------------------------------------------------------------
__global__ __launch_bounds__(256, 4) void cell_gemm3(
    const unsigned short* __restrict__ Abuf,
    const unsigned short* __restrict__ QB, const int* __restrict__ qoff,
    float* __restrict__ out, int cpb, int HW, int Qstride)
{
    __shared__ unsigned short Bsm[304 * 40];   // 24320 B

    const int tid = threadIdx.x;
    const int b   = blockIdx.x / cpb;
    const int c0  = (blockIdx.x - b * cpb) * 64;
    const size_t gc0 = (size_t)b * HW + c0;
    const int q0 = qoff[b];
    int qlen = qoff[b + 1] - q0; if (qlen < 1) qlen = 1;

    const int wid = tid >> 6, lane = tid & 63, quad = lane >> 4, l16 = lane & 15;

    // A-fragment pointer: row = c0 + wid*16 + l16, col base quad*8
    const unsigned short* aptr = Abuf + (gc0 + wid * 16 + l16) * 256 + quad * 8;
    bf16x8 afA = *(const bf16x8*)aptr;          // k0 = 0 fragment
    f32x4 acc[19] = {};

    for (int k0 = 0; k0 < 256; k0 += 32) {
        // stage B: 304 q-rows x 32 k bf16, padded stride 40
        for (int c = tid; c < 1216; c += 256) {
            int row = c >> 2, kc = (c & 3) * 8;
            int qr = row < qlen ? row : qlen - 1;
            uint4 v = *(const uint4*)(QB + (size_t)(q0 + qr) * 256 + k0 + kc);
            *(uint4*)&Bsm[row * 40 + kc] = v;
        }
        int k1 = (k0 + 32) & 255;               // wraps harmlessly on last iter
        bf16x8 afB = *(const bf16x8*)(aptr + k1);
        __syncthreads();
        #pragma unroll
        for (int t = 0; t < 19; ++t) {
            bf16x8 bfr = *(const bf16x8*)&Bsm[(t * 16 + l16) * 40 + quad * 8];
            acc[t] = __builtin_amdgcn_mfma_f32_16x16x32_bf16(afA, bfr, acc[t], 0, 0, 0);
        }
        __syncthreads();
        afA = afB;
    }

    // coalesced stores; zero-fill n >= qlen (no memset of d_out needed)
    #pragma unroll
    for (int r = 0; r < 4; ++r) {
        int m = quad * 4 + r;
        float* dst = out + (gc0 + wid * 16 + m) * Qstride;
        #pragma unroll
        for (int t = 0; t < 19; ++t) {
            int nq = t * 16 + l16;
            if (nq < Qstride) dst[nq] = (nq < qlen) ? acc[t][r] : 0.f;
        }
    }
}

extern "C" void kernel_launch(void* const* d_in, const int* in_sizes, int n_in,
                              void* d_out, int out_size, void* d_ws, size_t ws_size,
                              hipStream_t stream) {
    const float* queries = (const float*)d_in[0];
    const float* FV      = (const float*)d_in[1];
    const int*   FI      = (const int*)d_in[2];
    const int*   qoff    = (const int*)d_in[3];
    const int*   wptr    = (const int*)d_in[6];
    const float* W0 = (const float*)d_in[7];
    const float* b0 = (const float*)d_in[8];
    const float* W1 = (const float*)d_in[9];
    const float* b1 = (const float*)d_in[10];
    const float* W2 = (const float*)d_in[11];
    const float* b2 = (const float*)d_in[12];
    const float* W3 = (const float*)d_in[13];
    const float* b3 = (const float*)d_in[14];
    float* out = (float*)d_out;

    const int NQe = in_sizes[0];          // 307200
    const int NQ  = NQe / 256;            // 1200
    const int NF  = in_sizes[1] / 256;    // 65536
    const int WSZ = in_sizes[7];          // 65536
    const int B   = in_sizes[3] - 1;      // 4
    const int Q   = NQ / B;               // 300
    const int HW  = out_size / (B * Q);   // 16384
    const int NC  = B * HW;               // 65536 cells
    const int cpb = HW / 64;              // 256 blocks per batch

    int* cnt   = (int*)d_ws;                                   // NC ints
    int* slots = cnt + (size_t)NC;                             // NC*16 ints
    unsigned short* wsW  = (unsigned short*)(slots + (size_t)NC * 16);  // 4*WSZ
    unsigned short* wsQB = wsW + (size_t)4 * WSZ;              // NQe bf16
    unsigned short* Abuf = wsQB + (size_t)NQe;                 // NC*256 bf16

    hipMemsetAsync(cnt, 0, (size_t)NC * sizeof(int), stream);

    const int nbBin = (NF + 255) / 256;
    const int nbW   = (4 * WSZ / 4 + 255) / 256;
    prep<<<nbBin + nbW, 256, 0, stream>>>(FI, wptr, cnt, slots,
                                          W0, W1, W2, W3, wsW, NF, HW, WSZ, nbBin);

    const int nbM = (NQ + 15) / 16;       // 75 mlp blocks
    const int nbG = 4096;                 // gather blocks (half-wave per cell)
    gather_mlp<<<nbM + nbG, 256, 0, stream>>>(
        queries, wsW, b0, b1, b2, b3, wsQB, NQ, WSZ,
        FV, cnt, slots, Abuf, NC, nbM, nbG);

    cell_gemm3<<<B * cpb, 256, 0, stream>>>(Abuf, wsQB, qoff, out, cpb, HW, Q);
}